// Round 1
// baseline (122.827 us; speedup 1.0000x reference)
//
#include <hip/hip_runtime.h>
#include <hip/hip_bf16.h>

// ExplicitInterClassGraphLoss on MI355X (gfx950)
//   loss = mean_{i,j} (fn_i . fn_j - zg[lbl_i, lbl_j])^2,  fn = row-normalized feat
// Plan: (1) normalize fp32->bf16 into ws, (2) fused bf16 MFMA "GEMM" over
// upper-triangular 128x128 block pairs with in-epilogue zg subtraction and
// squared-diff accumulation, (3) finalize reduction of per-block partials.

typedef __attribute__((ext_vector_type(8))) short bf16x8;
typedef __attribute__((ext_vector_type(4))) float f32x4;

#define NROW 8192
#define DIM  512
#define NBIN 40
#define NBLK 64              // 8192 / 128
#define NPAIR (NBLK*(NBLK+1)/2)   // 2080

__device__ __forceinline__ unsigned short f2bf(float x) {
  __hip_bfloat16 h = __float2bfloat16(x);
  union { __hip_bfloat16 h; unsigned short u; } cv;
  cv.h = h;
  return cv.u;
}

// ---------------- kernel 1: row L2-normalize, fp32 -> bf16 ----------------
// one wave per row, 4 waves/block, 2048 blocks
__global__ __launch_bounds__(256) void rownorm_kernel(const float* __restrict__ feat,
                                                      __hip_bfloat16* __restrict__ fn) {
  int wid  = threadIdx.x >> 6;
  int lane = threadIdx.x & 63;
  int row  = blockIdx.x * 4 + wid;
  const float4* src = (const float4*)(feat + (size_t)row * DIM);
  float4 a = src[lane];
  float4 b = src[lane + 64];
  float s = a.x*a.x + a.y*a.y + a.z*a.z + a.w*a.w
          + b.x*b.x + b.y*b.y + b.z*b.z + b.w*b.w;
#pragma unroll
  for (int off = 1; off < 64; off <<= 1) s += __shfl_xor(s, off, 64);
  float scale = 1.0f / fmaxf(sqrtf(s), 1e-8f);
  ushort4 o0, o1;
  o0.x = f2bf(a.x * scale); o0.y = f2bf(a.y * scale);
  o0.z = f2bf(a.z * scale); o0.w = f2bf(a.w * scale);
  o1.x = f2bf(b.x * scale); o1.y = f2bf(b.y * scale);
  o1.z = f2bf(b.z * scale); o1.w = f2bf(b.w * scale);
  ushort4* dst = (ushort4*)(fn + (size_t)row * DIM);
  dst[lane]      = o0;
  dst[lane + 64] = o1;
}

// ---------------- kernel 2: fused loss over one 128x128 tile pair ----------------
// m97-structure: BK=32, global_load_lds width=16 staging, 4 waves (2x2 of 64x64),
// 16x16x32 bf16 MFMA, acc[4][4] f32x4 per wave. Epilogue subtracts zg, squares,
// reduces to one double partial per block. Upper-tri block enumeration, off-diag x2.
__global__ __launch_bounds__(256) void loss_kernel(const __hip_bfloat16* __restrict__ fn,
                                                   const int* __restrict__ label,
                                                   double* __restrict__ partials) {
  __shared__ __hip_bfloat16 As[128 * 32];
  __shared__ __hip_bfloat16 Bs[128 * 32];
  __shared__ float zg[NBIN * NBIN];
  __shared__ int   lbl[256];
  __shared__ float wsum[4];

  const int tid  = threadIdx.x;
  const int wid  = tid >> 6;
  const int lane = tid & 63;

  // --- map linear block id -> upper-triangular pair (bi <= bj) ---
  // S(b) = b*64 - b*(b-1)/2  (start index of row b)
  int t = blockIdx.x;
  int bi = 0;
  while (bi < NBLK - 1 && (bi + 1) * NBLK - ((bi + 1) * bi) / 2 <= t) bi++;
  int bj = bi + (t - (bi * NBLK - (bi * (bi - 1)) / 2));
  const int i0 = bi * 128;
  const int j0 = bj * 128;

  // --- build zg table + stage labels (consumed only in epilogue) ---
  for (int idx = tid; idx < NBIN * NBIN; idx += 256) {
    int a = idx / NBIN, b = idx - a * NBIN;
    float d = fabsf((float)(a - b)) * (float)(1.5707963267948966 / (NBIN - 1));
    float c = cosf(d);
    zg[idx] = fminf(fmaxf(c, 0.0f), 1.0f);
  }
  if (tid < 128) lbl[tid] = label[i0 + tid];
  else           lbl[tid] = label[j0 + (tid - 128)];

  const int wr = wid >> 1;   // wave row  (0..1) -> 64-row slab
  const int wc = wid & 1;    // wave col  (0..1) -> 64-col slab

  f32x4 acc[4][4] = {};

  // K loop: 512 / 32 = 16 steps
  for (int kt = 0; kt < 16; ++kt) {
    const int k0 = kt * 32;
    // stage As (rows of block bi) and Bs (rows of block bj):
    // linear 16B-chunk index L = q*256 + wid*64 + lane; elem = L*8;
    // row = L/4, col = (L%4)*8  -> LDS row-major [128][32]
#pragma unroll
    for (int q = 0; q < 2; ++q) {
      const int L   = q * 256 + wid * 64 + lane;
      const int row = L >> 2;
      const int col = (L & 3) * 8;
      const int dstOff = (q * 256 + wid * 64) * 16;  // wave-uniform byte base
      const __hip_bfloat16* gA = fn + (size_t)(i0 + row) * DIM + k0 + col;
      const __hip_bfloat16* gB = fn + (size_t)(j0 + row) * DIM + k0 + col;
      __builtin_amdgcn_global_load_lds(
          (const __attribute__((address_space(1))) void*)gA,
          (__attribute__((address_space(3))) void*)((char*)As + dstOff), 16, 0, 0);
      __builtin_amdgcn_global_load_lds(
          (const __attribute__((address_space(1))) void*)gB,
          (__attribute__((address_space(3))) void*)((char*)Bs + dstOff), 16, 0, 0);
    }
    __syncthreads();   // compiler drains vmcnt(0) before barrier

    bf16x8 af[4], bfr[4];
#pragma unroll
    for (int m = 0; m < 4; ++m)
      af[m] = *(const bf16x8*)&As[(wr * 64 + m * 16 + (lane & 15)) * 32 + (lane >> 4) * 8];
#pragma unroll
    for (int n = 0; n < 4; ++n)
      bfr[n] = *(const bf16x8*)&Bs[(wc * 64 + n * 16 + (lane & 15)) * 32 + (lane >> 4) * 8];
#pragma unroll
    for (int m = 0; m < 4; ++m)
#pragma unroll
      for (int n = 0; n < 4; ++n)
        acc[m][n] = __builtin_amdgcn_mfma_f32_16x16x32_bf16(af[m], bfr[n], acc[m][n], 0, 0, 0);
    __syncthreads();   // protect LDS before next stage
  }

  // --- epilogue: diff = acc - zg[lbl_i][lbl_j]; sum of squares ---
  // C/D mapping (m89): col = lane&15, row = (lane>>4)*4 + reg.
  // (Any transpose here is harmless: both matrices are symmetric.)
  const int ccol  = lane & 15;
  const int rbase = (lane >> 4) * 4;
  float lsum = 0.0f;
#pragma unroll
  for (int n = 0; n < 4; ++n) {
    const int lj = lbl[128 + wc * 64 + n * 16 + ccol];
#pragma unroll
    for (int m = 0; m < 4; ++m) {
#pragma unroll
      for (int r = 0; r < 4; ++r) {
        const int li = lbl[wr * 64 + m * 16 + rbase + r];
        float d = acc[m][n][r] - zg[li * NBIN + lj];
        lsum += d * d;
      }
    }
  }
  if (bi != bj) lsum *= 2.0f;   // off-diagonal tile counted twice

#pragma unroll
  for (int off = 1; off < 64; off <<= 1) lsum += __shfl_xor(lsum, off, 64);
  if (lane == 0) wsum[wid] = lsum;
  __syncthreads();
  if (tid == 0)
    partials[blockIdx.x] = (double)((wsum[0] + wsum[1]) + (wsum[2] + wsum[3]));
}

// ---------------- kernel 3: finalize ----------------
__global__ __launch_bounds__(256) void finalize_kernel(const double* __restrict__ partials,
                                                       int nblk, float* __restrict__ out) {
  __shared__ double wsh[4];
  int wid = threadIdx.x >> 6, lane = threadIdx.x & 63;
  double s = 0.0;
  for (int i = threadIdx.x; i < nblk; i += 256) s += partials[i];
#pragma unroll
  for (int off = 1; off < 64; off <<= 1) s += __shfl_xor(s, off, 64);
  if (lane == 0) wsh[wid] = s;
  __syncthreads();
  if (threadIdx.x == 0) {
    double tot = wsh[0] + wsh[1] + wsh[2] + wsh[3];
    out[0] = (float)(tot / ((double)NROW * (double)NROW));
  }
}

extern "C" void kernel_launch(void* const* d_in, const int* in_sizes, int n_in,
                              void* d_out, int out_size, void* d_ws, size_t ws_size,
                              hipStream_t stream) {
  const int*   label = (const int*)d_in[0];    // (8192,) int32
  const float* feat  = (const float*)d_in[1];  // (8192, 512) fp32
  float* out = (float*)d_out;

  char* ws = (char*)d_ws;
  __hip_bfloat16* fn = (__hip_bfloat16*)ws;                       // 8192*512*2 = 8 MiB
  double* partials = (double*)(ws + (size_t)NROW * DIM * 2);      // NPAIR doubles

  rownorm_kernel<<<NROW / 4, 256, 0, stream>>>(feat, fn);
  loss_kernel<<<NPAIR, 256, 0, stream>>>(fn, label, partials);
  finalize_kernel<<<1, 256, 0, stream>>>(partials, NPAIR, out);
}

// Round 3
// 118.878 us; speedup vs baseline: 1.0332x; 1.0332x over previous
//
#include <hip/hip_runtime.h>
#include <hip/hip_bf16.h>

// ExplicitInterClassGraphLoss on MI355X (gfx950)
//   loss = mean_{i,j} (fn_i . fn_j - zg[lbl_i, lbl_j])^2,  fn = row-normalized feat
// R2 = R1 resubmitted (infra timeout, no measurement): XOR-swizzle LDS chunk
// index (both-sides: pre-swizzled global source for global_load_lds + swizzled
// ds_read) to kill the bank conflict of the 64B-row-stride tile.

typedef __attribute__((ext_vector_type(8))) short bf16x8;
typedef __attribute__((ext_vector_type(4))) float f32x4;

#define NROW 8192
#define DIM  512
#define NBIN 40
#define NBLK 64              // 8192 / 128
#define NPAIR (NBLK*(NBLK+1)/2)   // 2080

__device__ __forceinline__ unsigned short f2bf(float x) {
  __hip_bfloat16 h = __float2bfloat16(x);
  union { __hip_bfloat16 h; unsigned short u; } cv;
  cv.h = h;
  return cv.u;
}

// ---------------- kernel 1: row L2-normalize, fp32 -> bf16 ----------------
__global__ __launch_bounds__(256) void rownorm_kernel(const float* __restrict__ feat,
                                                      __hip_bfloat16* __restrict__ fn) {
  int wid  = threadIdx.x >> 6;
  int lane = threadIdx.x & 63;
  int row  = blockIdx.x * 4 + wid;
  const float4* src = (const float4*)(feat + (size_t)row * DIM);
  float4 a = src[lane];
  float4 b = src[lane + 64];
  float s = a.x*a.x + a.y*a.y + a.z*a.z + a.w*a.w
          + b.x*b.x + b.y*b.y + b.z*b.z + b.w*b.w;
#pragma unroll
  for (int off = 1; off < 64; off <<= 1) s += __shfl_xor(s, off, 64);
  float scale = 1.0f / fmaxf(sqrtf(s), 1e-8f);
  ushort4 o0, o1;
  o0.x = f2bf(a.x * scale); o0.y = f2bf(a.y * scale);
  o0.z = f2bf(a.z * scale); o0.w = f2bf(a.w * scale);
  o1.x = f2bf(b.x * scale); o1.y = f2bf(b.y * scale);
  o1.z = f2bf(b.z * scale); o1.w = f2bf(b.w * scale);
  ushort4* dst = (ushort4*)(fn + (size_t)row * DIM);
  dst[lane]      = o0;
  dst[lane + 64] = o1;
}

// ---------------- kernel 2: fused loss over one 128x128 tile pair ----------------
// m97-structure: BK=32, global_load_lds width=16, 4 waves (2x2 of 64x64),
// 16x16x32 bf16 MFMA, acc[4][4] f32x4/wave. LDS tile [128][4 chunks of 8 bf16]
// with chunk' = chunk ^ ((row>>1)&3) swizzle (involution, applied on BOTH the
// global source col during staging and the ds_read address).
__global__ __launch_bounds__(256) void loss_kernel(const __hip_bfloat16* __restrict__ fn,
                                                   const int* __restrict__ label,
                                                   double* __restrict__ partials) {
  __shared__ __hip_bfloat16 As[128 * 32];
  __shared__ __hip_bfloat16 Bs[128 * 32];
  __shared__ float zg[NBIN * NBIN];
  __shared__ int   lbl[256];
  __shared__ float wsum[4];

  const int tid  = threadIdx.x;
  const int wid  = tid >> 6;
  const int lane = tid & 63;

  // --- map linear block id -> upper-triangular pair (bi <= bj) ---
  int t = blockIdx.x;
  int bi = 0;
  while (bi < NBLK - 1 && (bi + 1) * NBLK - ((bi + 1) * bi) / 2 <= t) bi++;
  int bj = bi + (t - (bi * NBLK - (bi * (bi - 1)) / 2));
  const int i0 = bi * 128;
  const int j0 = bj * 128;

  // --- build zg table + stage labels (consumed only in epilogue) ---
  for (int idx = tid; idx < NBIN * NBIN; idx += 256) {
    int a = idx / NBIN, b = idx - a * NBIN;
    float d = fabsf((float)(a - b)) * (float)(1.5707963267948966 / (NBIN - 1));
    float c = cosf(d);
    zg[idx] = fminf(fmaxf(c, 0.0f), 1.0f);
  }
  if (tid < 128) lbl[tid] = label[i0 + tid];
  else           lbl[tid] = label[j0 + (tid - 128)];

  const int wr = wid >> 1;   // wave row (0..1) -> 64-row slab
  const int wc = wid & 1;    // wave col (0..1) -> 64-col slab

  f32x4 acc[4][4] = {};

  // precompute per-lane staging geometry (row/chunk fixed across K-steps)
  // L = q*256 + wid*64 + lane ; row = L>>2 ; c_lds = L&3
  // source chunk c_g = c_lds ^ ((row>>1)&3)  (same XOR as read side)
  int srow[2], scol[2], sdst[2];
#pragma unroll
  for (int q = 0; q < 2; ++q) {
    const int L   = q * 256 + wid * 64 + lane;
    const int row = L >> 2;
    const int c_g = (L & 3) ^ ((row >> 1) & 3);
    srow[q] = row;
    scol[q] = c_g * 8;
    sdst[q] = (q * 256 + wid * 64) * 16;  // wave-uniform byte base
  }

  // K loop: 512 / 32 = 16 steps
  for (int kt = 0; kt < 16; ++kt) {
    const int k0 = kt * 32;
#pragma unroll
    for (int q = 0; q < 2; ++q) {
      const __hip_bfloat16* gA = fn + (size_t)(i0 + srow[q]) * DIM + k0 + scol[q];
      const __hip_bfloat16* gB = fn + (size_t)(j0 + srow[q]) * DIM + k0 + scol[q];
      __builtin_amdgcn_global_load_lds(
          (const __attribute__((address_space(1))) void*)gA,
          (__attribute__((address_space(3))) void*)((char*)As + sdst[q]), 16, 0, 0);
      __builtin_amdgcn_global_load_lds(
          (const __attribute__((address_space(1))) void*)gB,
          (__attribute__((address_space(3))) void*)((char*)Bs + sdst[q]), 16, 0, 0);
    }
    __syncthreads();   // compiler drains vmcnt(0) before barrier

    bf16x8 af[4], bfr[4];
    const int fs = lane & 15;        // fragment row-in-16
    const int fc = lane >> 4;        // fragment K-chunk (0..3)
#pragma unroll
    for (int m = 0; m < 4; ++m) {
      const int r = wr * 64 + m * 16 + fs;
      af[m] = *(const bf16x8*)&As[r * 32 + (fc ^ ((r >> 1) & 3)) * 8];
    }
#pragma unroll
    for (int n = 0; n < 4; ++n) {
      const int r = wc * 64 + n * 16 + fs;
      bfr[n] = *(const bf16x8*)&Bs[r * 32 + (fc ^ ((r >> 1) & 3)) * 8];
    }
#pragma unroll
    for (int m = 0; m < 4; ++m)
#pragma unroll
      for (int n = 0; n < 4; ++n)
        acc[m][n] = __builtin_amdgcn_mfma_f32_16x16x32_bf16(af[m], bfr[n], acc[m][n], 0, 0, 0);
    __syncthreads();   // protect LDS before next stage
  }

  // --- epilogue: diff = acc - zg[lbl_i][lbl_j]; sum of squares ---
  // C/D mapping (m89): col = lane&15, row = (lane>>4)*4 + reg.
  // (Transpose-safe: both matrices symmetric.)
  const int ccol  = lane & 15;
  const int rbase = (lane >> 4) * 4;
  float lsum = 0.0f;
#pragma unroll
  for (int n = 0; n < 4; ++n) {
    const int lj = lbl[128 + wc * 64 + n * 16 + ccol];
#pragma unroll
    for (int m = 0; m < 4; ++m) {
#pragma unroll
      for (int r = 0; r < 4; ++r) {
        const int li = lbl[wr * 64 + m * 16 + rbase + r];
        float d = acc[m][n][r] - zg[li * NBIN + lj];
        lsum += d * d;
      }
    }
  }
  if (bi != bj) lsum *= 2.0f;   // off-diagonal tile counted twice

#pragma unroll
  for (int off = 1; off < 64; off <<= 1) lsum += __shfl_xor(lsum, off, 64);
  if (lane == 0) wsum[wid] = lsum;
  __syncthreads();
  if (tid == 0)
    partials[blockIdx.x] = (double)((wsum[0] + wsum[1]) + (wsum[2] + wsum[3]));
}

// ---------------- kernel 3: finalize ----------------
__global__ __launch_bounds__(256) void finalize_kernel(const double* __restrict__ partials,
                                                       int nblk, float* __restrict__ out) {
  __shared__ double wsh[4];
  int wid = threadIdx.x >> 6, lane = threadIdx.x & 63;
  double s = 0.0;
  for (int i = threadIdx.x; i < nblk; i += 256) s += partials[i];
#pragma unroll
  for (int off = 1; off < 64; off <<= 1) s += __shfl_xor(s, off, 64);
  if (lane == 0) wsh[wid] = s;
  __syncthreads();
  if (threadIdx.x == 0) {
    double tot = wsh[0] + wsh[1] + wsh[2] + wsh[3];
    out[0] = (float)(tot / ((double)NROW * (double)NROW));
  }
}

extern "C" void kernel_launch(void* const* d_in, const int* in_sizes, int n_in,
                              void* d_out, int out_size, void* d_ws, size_t ws_size,
                              hipStream_t stream) {
  const int*   label = (const int*)d_in[0];    // (8192,) int32
  const float* feat  = (const float*)d_in[1];  // (8192, 512) fp32
  float* out = (float*)d_out;

  char* ws = (char*)d_ws;
  __hip_bfloat16* fn = (__hip_bfloat16*)ws;                       // 8 MiB
  double* partials = (double*)(ws + (size_t)NROW * DIM * 2);      // NPAIR doubles

  rownorm_kernel<<<NROW / 4, 256, 0, stream>>>(feat, fn);
  loss_kernel<<<NPAIR, 256, 0, stream>>>(fn, label, partials);
  finalize_kernel<<<1, 256, 0, stream>>>(partials, NPAIR, out);
}